// Round 4
// baseline (341.784 us; speedup 1.0000x reference)
//
#include <hip/hip_runtime.h>
#include <hip/hip_bf16.h>
#include <math.h>

#define NN   50000
#define EE   800000
#define INF  512
#define HIDF 256
#define OUTF 64
#define MTILES (NN/16)   // 3125

using short8 = __attribute__((ext_vector_type(8))) short;
using short4v = __attribute__((ext_vector_type(4))) short;
using f32x4  = __attribute__((ext_vector_type(4))) float;

typedef __attribute__((address_space(1))) const void gas_void;
typedef __attribute__((address_space(3))) void las_void;

static __device__ __forceinline__ short f2bf(float f){
  unsigned u = __builtin_bit_cast(unsigned, f);
  u += 0x7fff + ((u >> 16) & 1);        // round-to-nearest-even
  return (short)(u >> 16);
}
static __device__ __forceinline__ float bf2f(short s){
  unsigned u = ((unsigned)(unsigned short)s) << 16;
  return __builtin_bit_cast(float, u);
}

// ---- fused prep: row_ptr (blocks 0..195) | W1 pack (196..707) | W2^T (708..771) ----
__global__ void k_prep(const int* __restrict__ a_row, int* __restrict__ row_ptr,
                       const float* __restrict__ W1, short* __restrict__ W1p,
                       const float* __restrict__ W2, short* __restrict__ W2bT){
  int b = blockIdx.x, tid = threadIdx.x;
  if (b < 196){
    int i = b * 256 + tid;
    if (i > NN) return;
    int lo = 0, hi = EE;
    while (lo < hi){ int mid = (lo + hi) >> 1; if (a_row[mid] < i) lo = mid + 1; else hi = mid; }
    row_ptr[i] = lo;
  } else if (b < 708){
    int idx = (b - 196) * 256 + tid;        // 512*256 elements
    int k = idx >> 8, col = idx & 255;
    int kk = k >> 5, k2 = k & 31;
    W1p[((kk << 8) + col) * 32 + k2] = f2bf(W1[idx]);
  } else {
    int idx = (b - 708) * 256 + tid;        // 256*64 elements
    int k = idx >> 6, n = idx & 63;
    W2bT[n * HIDF + k] = f2bf(W2[idx]);
  }
}

// ---------------- GEMM1: XW1b[NN,HIDF](bf16) = X[NN,INF] @ W1 ----------------
// 2-phase pipelined (guide §5.5 T3 minimum form) — validated round 2.
__global__ __launch_bounds__(256) void k_gemm1(const float* __restrict__ X,
                                               const short* __restrict__ W1p,
                                               short* __restrict__ XW1b){
  __shared__ short lds[2][256 * 32];          // 2 x 16 KB B panels
  int wave = threadIdx.x >> 6, lane = threadIdx.x & 63;
  int l16 = lane & 15, quad = lane >> 4;
  int m0 = blockIdx.x * 64 + wave * 16;       // 16 rows per wave
  int r = min(m0 + l16, NN - 1);              // clamp loads; stores guarded
  const float4* ap = (const float4*)(X + (size_t)r * INF + quad * 8);

  f32x4 acc[16];
  #pragma unroll
  for (int t = 0; t < 16; t++) acc[t] = (f32x4){0.f,0.f,0.f,0.f};

  auto stage = [&](int buf, int kk){
    const char* src = (const char*)(W1p + kk * (256 * 32));
    char* dst = (char*)&lds[buf][0];
    #pragma unroll
    for (int j = 0; j < 4; j++){
      int off = wave * 4096 + j * 1024;
      __builtin_amdgcn_global_load_lds((gas_void*)(src + off + lane * 16),
                                       (las_void*)(dst + off), 16, 0, 0);
    }
  };

  stage(0, 0);
  float4 a0 = ap[0], a1 = ap[1];
  __syncthreads();                            // drains vmcnt -> lds[0] ready

  for (int kk = 0; kk < 16; kk++){
    int cur = kk & 1;
    float4 na0, na1;
    if (kk < 15){
      stage(cur ^ 1, kk + 1);
      na0 = ap[(kk + 1) * 8];
      na1 = ap[(kk + 1) * 8 + 1];
    }
    short8 af;
    af[0]=f2bf(a0.x); af[1]=f2bf(a0.y); af[2]=f2bf(a0.z); af[3]=f2bf(a0.w);
    af[4]=f2bf(a1.x); af[5]=f2bf(a1.y); af[6]=f2bf(a1.z); af[7]=f2bf(a1.w);
    const short* bp = &lds[cur][0] + l16 * 32 + quad * 8;
    #pragma unroll
    for (int nt = 0; nt < 16; nt++){
      short8 bf = *(const short8*)(bp + nt * 512);   // (nt*16 cols) * 32 shorts
      acc[nt] = __builtin_amdgcn_mfma_f32_16x16x32_bf16(af, bf, acc[nt], 0, 0, 0);
    }
    a0 = na0; a1 = na1;
    __syncthreads();                          // next panel arrived; cur free to reuse
  }

  #pragma unroll
  for (int nt = 0; nt < 16; nt++){
    int col = nt*16 + l16;
    #pragma unroll
    for (int rr = 0; rr < 4; rr++){
      int row = m0 + quad*4 + rr;
      if (row < NN) XW1b[(size_t)row * HIDF + col] = f2bf(acc[nt][rr]);
    }
  }
}

// ---- SpMM1 + ReLU + dropout: one wave/row, 4 edge-groups x 16 lanes x 32B ----
// BATCHED gather (round-3 lesson): cross-iteration pipelining is legally
// collapsed by LLVM (loads sunk to uses; round-3 VGPR=28).  Within ONE basic
// block the scheduler DOES hoist independent loads.  So: straight-line batch
// of 4 pipeline steps = 8 scalar loads, then 8 independent gathers, then 128
// FMAs.  Latency paid ~2x per 16 edges instead of 2x per 4 edges.
__global__ __launch_bounds__(256) void k_spmm1(const int* __restrict__ row_ptr,
                                               const int* __restrict__ a_col,
                                               const float* __restrict__ a_val,
                                               const short* __restrict__ XW1b,
                                               const int* __restrict__ drop_mask,
                                               short* __restrict__ hb){
  int wave = threadIdx.x >> 6, lane = threadIdx.x & 63;
  int r = blockIdx.x * 4 + wave;
  int s = row_ptr[r], e = row_ptr[r+1];
  int g = lane >> 4;          // edge subgroup
  int c16 = lane & 15;        // this lane covers cols c16*16 .. +15
  float acc[16];
  #pragma unroll
  for (int j = 0; j < 16; j++) acc[j] = 0.f;

  int n = (e - s + 3) >> 2;   // wave-uniform per-group step count

  // predicated scalar-edge load: clamped address (always in-bounds), v=0 past end
  auto ldcv = [&](int t, float& v, int& c){
    int idx = s + g + t * 4;
    int ic = idx < e ? idx : (EE - 1);
    float vv = a_val[ic];
    c = a_col[ic];
    v = idx < e ? vv : 0.f;
  };

  for (int t = 0; t < n; t += 4){
    // phase 1: 8 independent predicated scalar loads (one latency)
    float v0, v1, v2, v3; int c0, c1, c2, c3;
    ldcv(t,     v0, c0);
    ldcv(t + 1, v1, c1);
    ldcv(t + 2, v2, c2);
    ldcv(t + 3, v3, c3);
    // phase 2: 8 independent gathers (one latency, all in flight together)
    const short* p0 = XW1b + (size_t)c0 * HIDF + c16 * 16;
    const short* p1 = XW1b + (size_t)c1 * HIDF + c16 * 16;
    const short* p2 = XW1b + (size_t)c2 * HIDF + c16 * 16;
    const short* p3 = XW1b + (size_t)c3 * HIDF + c16 * 16;
    short8 xa0 = *(const short8*)(p0), xb0 = *(const short8*)(p0 + 8);
    short8 xa1 = *(const short8*)(p1), xb1 = *(const short8*)(p1 + 8);
    short8 xa2 = *(const short8*)(p2), xb2 = *(const short8*)(p2 + 8);
    short8 xa3 = *(const short8*)(p3), xb3 = *(const short8*)(p3 + 8);
    // phase 3: FMA block
    #pragma unroll
    for (int j = 0; j < 8; j++){
      acc[j]   += v0 * bf2f(xa0[j]);  acc[j+8] += v0 * bf2f(xb0[j]);
      acc[j]   += v1 * bf2f(xa1[j]);  acc[j+8] += v1 * bf2f(xb1[j]);
      acc[j]   += v2 * bf2f(xa2[j]);  acc[j+8] += v2 * bf2f(xb2[j]);
      acc[j]   += v3 * bf2f(xa3[j]);  acc[j+8] += v3 * bf2f(xb3[j]);
    }
  }

  #pragma unroll
  for (int j = 0; j < 16; j++){
    acc[j] += __shfl_xor(acc[j], 16);
    acc[j] += __shfl_xor(acc[j], 32);
  }
  if (lane < 16){
    const int* dm = drop_mask + (size_t)r * HIDF + c16 * 16;
    short8 o0, o1;
    #pragma unroll
    for (int j = 0; j < 8; j++){
      o0[j] = f2bf(fmaxf(acc[j],   0.f) * (float)dm[j]   * 2.0f);
      o1[j] = f2bf(fmaxf(acc[j+8], 0.f) * (float)dm[j+8] * 2.0f);
    }
    short* hp = hb + (size_t)r * HIDF + c16 * 16;
    *(short8*)(hp)     = o0;
    *(short8*)(hp + 8) = o1;
  }
}

// ---------------- GEMM2: HW2b[NN,OUTF](bf16) = h[NN,HIDF] @ W2 ----------------
__global__ __launch_bounds__(256) void k_gemm2(const short* __restrict__ A,  // hb
                                               const short* __restrict__ BT, // [OUTF][HIDF]
                                               short* __restrict__ C){
  int wave = threadIdx.x >> 6, lane = threadIdx.x & 63;
  int tile_m = blockIdx.x * 4 + wave;
  if (tile_m >= MTILES) return;
  int m0 = tile_m * 16, l16 = lane & 15, quad = lane >> 4;

  f32x4 acc[4];
  #pragma unroll
  for (int t = 0; t < 4; t++) acc[t] = (f32x4){0.f,0.f,0.f,0.f};

  const short* ar = A + (size_t)(m0 + l16) * HIDF + quad * 8;
  for (int kk = 0; kk < HIDF/32; kk++){
    short8 af = *(const short8*)(ar + kk * 32);
    #pragma unroll
    for (int nt = 0; nt < 4; nt++){
      short8 bf = *(const short8*)(BT + (size_t)(nt*16 + l16) * HIDF + kk*32 + quad*8);
      acc[nt] = __builtin_amdgcn_mfma_f32_16x16x32_bf16(af, bf, acc[nt], 0, 0, 0);
    }
  }
  #pragma unroll
  for (int nt = 0; nt < 4; nt++){
    int col = nt*16 + l16;
    #pragma unroll
    for (int r = 0; r < 4; r++)
      C[(size_t)(m0 + quad*4 + r) * OUTF + col] = f2bf(acc[nt][r]);
  }
}

// -- SpMM2 + log_softmax: one wave/row, 4 edge-groups x 16 lanes x 8B --
// Same straight-line batched-gather structure as k_spmm1.
__global__ __launch_bounds__(256) void k_spmm2_lsm(const int* __restrict__ row_ptr,
                                                   const int* __restrict__ a_col,
                                                   const float* __restrict__ a_val,
                                                   const short* __restrict__ HW2b,
                                                   float* __restrict__ out){
  int wave = threadIdx.x >> 6, lane = threadIdx.x & 63;
  int r = blockIdx.x * 4 + wave;
  int s = row_ptr[r], e = row_ptr[r+1];
  int g = lane >> 4;          // edge subgroup
  int c4 = lane & 15;         // this lane covers classes c4*4 .. c4*4+3
  float acc[4] = {0,0,0,0};

  int n = (e - s + 3) >> 2;

  auto ldcv = [&](int t, float& v, int& c){
    int idx = s + g + t * 4;
    int ic = idx < e ? idx : (EE - 1);
    float vv = a_val[ic];
    c = a_col[ic];
    v = idx < e ? vv : 0.f;
  };

  for (int t = 0; t < n; t += 4){
    float v0, v1, v2, v3; int c0, c1, c2, c3;
    ldcv(t,     v0, c0);
    ldcv(t + 1, v1, c1);
    ldcv(t + 2, v2, c2);
    ldcv(t + 3, v3, c3);
    short4v x0 = *(const short4v*)(HW2b + (size_t)c0 * OUTF + c4 * 4);
    short4v x1 = *(const short4v*)(HW2b + (size_t)c1 * OUTF + c4 * 4);
    short4v x2 = *(const short4v*)(HW2b + (size_t)c2 * OUTF + c4 * 4);
    short4v x3 = *(const short4v*)(HW2b + (size_t)c3 * OUTF + c4 * 4);
    #pragma unroll
    for (int j = 0; j < 4; j++){
      acc[j] += v0 * bf2f(x0[j]);
      acc[j] += v1 * bf2f(x1[j]);
      acc[j] += v2 * bf2f(x2[j]);
      acc[j] += v3 * bf2f(x3[j]);
    }
  }

  #pragma unroll
  for (int j = 0; j < 4; j++){
    acc[j] += __shfl_xor(acc[j], 16);
    acc[j] += __shfl_xor(acc[j], 32);
  }
  // log_softmax across 64 classes (all lanes now hold identical per-c4 values)
  float m = fmaxf(fmaxf(acc[0], acc[1]), fmaxf(acc[2], acc[3]));
  #pragma unroll
  for (int o = 1; o <= 8; o <<= 1) m = fmaxf(m, __shfl_xor(m, o));
  float ssum = expf(acc[0]-m) + expf(acc[1]-m) + expf(acc[2]-m) + expf(acc[3]-m);
  #pragma unroll
  for (int o = 1; o <= 8; o <<= 1) ssum += __shfl_xor(ssum, o);
  float ls = logf(ssum);
  if (lane < 16){
    float4 o4 = { acc[0]-m-ls, acc[1]-m-ls, acc[2]-m-ls, acc[3]-m-ls };
    *(float4*)(out + (size_t)r * OUTF + c4 * 4) = o4;
  }
}

extern "C" void kernel_launch(void* const* d_in, const int* in_sizes, int n_in,
                              void* d_out, int out_size, void* d_ws, size_t ws_size,
                              hipStream_t stream) {
  const float* X      = (const float*)d_in[0];
  const float* W1     = (const float*)d_in[1];
  const float* W2     = (const float*)d_in[2];
  const int*   a_row  = (const int*)d_in[3];
  const int*   a_col  = (const int*)d_in[4];
  const float* a_val  = (const float*)d_in[5];
  const int*   drop   = (const int*)d_in[6];
  float*       out    = (float*)d_out;

  char* ws = (char*)d_ws;
  int*   row_ptr = (int*)  (ws);                       //   200,704 B
  short* W1p     = (short*)(ws + 200704);              //   262,144 B
  short* W2bT    = (short*)(ws + 462848);              //    32,768 B
  short* XW1b    = (short*)(ws + 495616);              // 25,600,000 B
  short* hb      = (short*)(ws + 26095616);            // 25,600,000 B
  short* HW2b    = (short*)(ws + 51695616);            //  6,400,000 B (end ~58.1 MB)

  k_prep<<<772, 256, 0, stream>>>(a_row, row_ptr, W1, W1p, W2, W2bT);
  k_gemm1<<<(NN + 63)/64, 256, 0, stream>>>(X, W1p, XW1b);
  k_spmm1<<<NN/4, 256, 0, stream>>>(row_ptr, a_col, a_val, XW1b, drop, hb);
  k_gemm2<<<(MTILES + 3)/4, 256, 0, stream>>>(hb, W2bT, HW2b);
  k_spmm2_lsm<<<NN/4, 256, 0, stream>>>(row_ptr, a_col, a_val, HW2b, out);
}

// Round 5
// 317.084 us; speedup vs baseline: 1.0779x; 1.0779x over previous
//
#include <hip/hip_runtime.h>
#include <hip/hip_bf16.h>
#include <math.h>

#define NN   50000
#define EE   800000
#define INF  512
#define HIDF 256
#define OUTF 64
#define MTILES (NN/16)   // 3125

using short8 = __attribute__((ext_vector_type(8))) short;
using short4v = __attribute__((ext_vector_type(4))) short;
using f32x4  = __attribute__((ext_vector_type(4))) float;

typedef __attribute__((address_space(1))) const void gas_void;
typedef __attribute__((address_space(3))) void las_void;

static __device__ __forceinline__ short f2bf(float f){
  unsigned u = __builtin_bit_cast(unsigned, f);
  u += 0x7fff + ((u >> 16) & 1);        // round-to-nearest-even
  return (short)(u >> 16);
}
static __device__ __forceinline__ float bf2f(short s){
  unsigned u = ((unsigned)(unsigned short)s) << 16;
  return __builtin_bit_cast(float, u);
}

// ---- fused prep: row_ptr (blocks 0..195) | W1 pack (196..707) | W2^T (708..771) ----
__global__ void k_prep(const int* __restrict__ a_row, int* __restrict__ row_ptr,
                       const float* __restrict__ W1, short* __restrict__ W1p,
                       const float* __restrict__ W2, short* __restrict__ W2bT){
  int b = blockIdx.x, tid = threadIdx.x;
  if (b < 196){
    int i = b * 256 + tid;
    if (i > NN) return;
    int lo = 0, hi = EE;
    while (lo < hi){ int mid = (lo + hi) >> 1; if (a_row[mid] < i) lo = mid + 1; else hi = mid; }
    row_ptr[i] = lo;
  } else if (b < 708){
    int idx = (b - 196) * 256 + tid;        // 512*256 elements
    int k = idx >> 8, col = idx & 255;
    int kk = k >> 5, k2 = k & 31;
    W1p[((kk << 8) + col) * 32 + k2] = f2bf(W1[idx]);
  } else {
    int idx = (b - 708) * 256 + tid;        // 256*64 elements
    int k = idx >> 6, n = idx & 63;
    W2bT[n * HIDF + k] = f2bf(W2[idx]);
  }
}

// ---------------- GEMM1: XW1b[NN,HIDF](bf16) = X[NN,INF] @ W1 ----------------
// 2-phase pipelined (guide §5.5 T3 minimum form) — validated round 2.
__global__ __launch_bounds__(256) void k_gemm1(const float* __restrict__ X,
                                               const short* __restrict__ W1p,
                                               short* __restrict__ XW1b){
  __shared__ short lds[2][256 * 32];          // 2 x 16 KB B panels
  int wave = threadIdx.x >> 6, lane = threadIdx.x & 63;
  int l16 = lane & 15, quad = lane >> 4;
  int m0 = blockIdx.x * 64 + wave * 16;       // 16 rows per wave
  int r = min(m0 + l16, NN - 1);              // clamp loads; stores guarded
  const float4* ap = (const float4*)(X + (size_t)r * INF + quad * 8);

  f32x4 acc[16];
  #pragma unroll
  for (int t = 0; t < 16; t++) acc[t] = (f32x4){0.f,0.f,0.f,0.f};

  auto stage = [&](int buf, int kk){
    const char* src = (const char*)(W1p + kk * (256 * 32));
    char* dst = (char*)&lds[buf][0];
    #pragma unroll
    for (int j = 0; j < 4; j++){
      int off = wave * 4096 + j * 1024;
      __builtin_amdgcn_global_load_lds((gas_void*)(src + off + lane * 16),
                                       (las_void*)(dst + off), 16, 0, 0);
    }
  };

  stage(0, 0);
  float4 a0 = ap[0], a1 = ap[1];
  __syncthreads();                            // drains vmcnt -> lds[0] ready

  for (int kk = 0; kk < 16; kk++){
    int cur = kk & 1;
    float4 na0, na1;
    if (kk < 15){
      stage(cur ^ 1, kk + 1);
      na0 = ap[(kk + 1) * 8];
      na1 = ap[(kk + 1) * 8 + 1];
    }
    short8 af;
    af[0]=f2bf(a0.x); af[1]=f2bf(a0.y); af[2]=f2bf(a0.z); af[3]=f2bf(a0.w);
    af[4]=f2bf(a1.x); af[5]=f2bf(a1.y); af[6]=f2bf(a1.z); af[7]=f2bf(a1.w);
    const short* bp = &lds[cur][0] + l16 * 32 + quad * 8;
    #pragma unroll
    for (int nt = 0; nt < 16; nt++){
      short8 bf = *(const short8*)(bp + nt * 512);   // (nt*16 cols) * 32 shorts
      acc[nt] = __builtin_amdgcn_mfma_f32_16x16x32_bf16(af, bf, acc[nt], 0, 0, 0);
    }
    a0 = na0; a1 = na1;
    __syncthreads();                          // next panel arrived; cur free to reuse
  }

  #pragma unroll
  for (int nt = 0; nt < 16; nt++){
    int col = nt*16 + l16;
    #pragma unroll
    for (int rr = 0; rr < 4; rr++){
      int row = m0 + quad*4 + rr;
      if (row < NN) XW1b[(size_t)row * HIDF + col] = f2bf(acc[nt][rr]);
    }
  }
}

// ---- SpMM1 + ReLU + dropout ----------------------------------------------
// Round-5 structure:
//  * ONE coalesced 64-edge preload of a_val/a_col per row (lane i holds edge
//    s+i); per-step edge scalars come via __shfl (ds_bpermute) — removes the
//    scalar-load latency from the gather chain entirely.  Out-of-range lanes
//    preload v=0, so predication is free.  d>64 handled by a fallback loop
//    (P(d>64) ~ 0 for this Poisson(16) edge distribution, but kept for
//    correctness).
//  * 4-edge steps (round-4's 16-edge batches inflated work ~28% vs ceil(d/4)
//    padding), unrolled 2 steps per straight-line block so 2 gather-pairs are
//    in flight together (round-4's ILP win, without its work inflation).
__global__ __launch_bounds__(256) void k_spmm1(const int* __restrict__ row_ptr,
                                               const int* __restrict__ a_col,
                                               const float* __restrict__ a_val,
                                               const short* __restrict__ XW1b,
                                               const int* __restrict__ drop_mask,
                                               short* __restrict__ hb){
  int wave = threadIdx.x >> 6, lane = threadIdx.x & 63;
  int r = blockIdx.x * 4 + wave;
  int s = row_ptr[r], e = row_ptr[r+1];
  int g = lane >> 4;          // edge subgroup (4 edges per step)
  int c16 = lane & 15;        // this lane covers cols c16*16 .. +15
  int d = e - s;

  int   lim = d < 64 ? d : 64;
  bool  lv  = lane < lim;
  float myv = lv ? a_val[s + lane] : 0.f;   // coalesced 64-edge preload
  int   myc = lv ? a_col[s + lane] : 0;

  float acc[16];
  #pragma unroll
  for (int j = 0; j < 16; j++) acc[j] = 0.f;

  int nsteps = (lim + 3) >> 2;              // 4 edges per step
  for (int t = 0; t < nsteps; t += 2){      // t always even; shfl idx <= 63
    int e0 = 4*t + g, e1 = 4*t + 4 + g;
    float v0 = __shfl(myv, e0);  int c0 = __shfl(myc, e0);
    float v1 = __shfl(myv, e1);  int c1 = __shfl(myc, e1);  // v=0 past row end
    const short* p0 = XW1b + (c0 << 8) + c16 * 16;          // c*HIDF fits int
    const short* p1 = XW1b + (c1 << 8) + c16 * 16;
    short8 xa0 = *(const short8*)(p0), xb0 = *(const short8*)(p0 + 8);
    short8 xa1 = *(const short8*)(p1), xb1 = *(const short8*)(p1 + 8);
    #pragma unroll
    for (int j = 0; j < 8; j++){
      acc[j]   += v0 * bf2f(xa0[j]);  acc[j+8] += v0 * bf2f(xb0[j]);
      acc[j]   += v1 * bf2f(xa1[j]);  acc[j+8] += v1 * bf2f(xb1[j]);
    }
  }
  if (d > 64){                              // correctness fallback, ~never taken
    for (int i = s + 64 + g; i < e; i += 4){
      float v = a_val[i];  int c = a_col[i];
      const short* p = XW1b + (c << 8) + c16 * 16;
      short8 xa = *(const short8*)(p), xb = *(const short8*)(p + 8);
      #pragma unroll
      for (int j = 0; j < 8; j++){
        acc[j] += v * bf2f(xa[j]);  acc[j+8] += v * bf2f(xb[j]);
      }
    }
  }

  #pragma unroll
  for (int j = 0; j < 16; j++){
    acc[j] += __shfl_xor(acc[j], 16);
    acc[j] += __shfl_xor(acc[j], 32);
  }
  if (lane < 16){
    const int* dm = drop_mask + (size_t)r * HIDF + c16 * 16;
    short8 o0, o1;
    #pragma unroll
    for (int j = 0; j < 8; j++){
      o0[j] = f2bf(fmaxf(acc[j],   0.f) * (float)dm[j]   * 2.0f);
      o1[j] = f2bf(fmaxf(acc[j+8], 0.f) * (float)dm[j+8] * 2.0f);
    }
    short* hp = hb + (size_t)r * HIDF + c16 * 16;
    *(short8*)(hp)     = o0;
    *(short8*)(hp + 8) = o1;
  }
}

// ---------------- GEMM2: HW2b[NN,OUTF](bf16) = h[NN,HIDF] @ W2 ----------------
__global__ __launch_bounds__(256) void k_gemm2(const short* __restrict__ A,  // hb
                                               const short* __restrict__ BT, // [OUTF][HIDF]
                                               short* __restrict__ C){
  int wave = threadIdx.x >> 6, lane = threadIdx.x & 63;
  int tile_m = blockIdx.x * 4 + wave;
  if (tile_m >= MTILES) return;
  int m0 = tile_m * 16, l16 = lane & 15, quad = lane >> 4;

  f32x4 acc[4];
  #pragma unroll
  for (int t = 0; t < 4; t++) acc[t] = (f32x4){0.f,0.f,0.f,0.f};

  const short* ar = A + (size_t)(m0 + l16) * HIDF + quad * 8;
  for (int kk = 0; kk < HIDF/32; kk++){
    short8 af = *(const short8*)(ar + kk * 32);
    #pragma unroll
    for (int nt = 0; nt < 4; nt++){
      short8 bf = *(const short8*)(BT + (size_t)(nt*16 + l16) * HIDF + kk*32 + quad*8);
      acc[nt] = __builtin_amdgcn_mfma_f32_16x16x32_bf16(af, bf, acc[nt], 0, 0, 0);
    }
  }
  #pragma unroll
  for (int nt = 0; nt < 4; nt++){
    int col = nt*16 + l16;
    #pragma unroll
    for (int r = 0; r < 4; r++)
      C[(size_t)(m0 + quad*4 + r) * OUTF + col] = f2bf(acc[nt][r]);
  }
}

// -- SpMM2 + log_softmax: same preload+shfl structure as k_spmm1 --
__global__ __launch_bounds__(256) void k_spmm2_lsm(const int* __restrict__ row_ptr,
                                                   const int* __restrict__ a_col,
                                                   const float* __restrict__ a_val,
                                                   const short* __restrict__ HW2b,
                                                   float* __restrict__ out){
  int wave = threadIdx.x >> 6, lane = threadIdx.x & 63;
  int r = blockIdx.x * 4 + wave;
  int s = row_ptr[r], e = row_ptr[r+1];
  int g = lane >> 4;          // edge subgroup
  int c4 = lane & 15;         // this lane covers classes c4*4 .. c4*4+3
  int d = e - s;

  int   lim = d < 64 ? d : 64;
  bool  lv  = lane < lim;
  float myv = lv ? a_val[s + lane] : 0.f;
  int   myc = lv ? a_col[s + lane] : 0;

  float acc[4] = {0,0,0,0};

  int nsteps = (lim + 3) >> 2;
  for (int t = 0; t < nsteps; t += 2){
    int e0 = 4*t + g, e1 = 4*t + 4 + g;
    float v0 = __shfl(myv, e0);  int c0 = __shfl(myc, e0);
    float v1 = __shfl(myv, e1);  int c1 = __shfl(myc, e1);
    short4v x0 = *(const short4v*)(HW2b + (c0 << 6) + c4 * 4);
    short4v x1 = *(const short4v*)(HW2b + (c1 << 6) + c4 * 4);
    #pragma unroll
    for (int j = 0; j < 4; j++){
      acc[j] += v0 * bf2f(x0[j]);
      acc[j] += v1 * bf2f(x1[j]);
    }
  }
  if (d > 64){
    for (int i = s + 64 + g; i < e; i += 4){
      float v = a_val[i];  int c = a_col[i];
      short4v x = *(const short4v*)(HW2b + (c << 6) + c4 * 4);
      #pragma unroll
      for (int j = 0; j < 4; j++) acc[j] += v * bf2f(x[j]);
    }
  }

  #pragma unroll
  for (int j = 0; j < 4; j++){
    acc[j] += __shfl_xor(acc[j], 16);
    acc[j] += __shfl_xor(acc[j], 32);
  }
  // log_softmax across 64 classes (all lanes now hold identical per-c4 values)
  float m = fmaxf(fmaxf(acc[0], acc[1]), fmaxf(acc[2], acc[3]));
  #pragma unroll
  for (int o = 1; o <= 8; o <<= 1) m = fmaxf(m, __shfl_xor(m, o));
  float ssum = expf(acc[0]-m) + expf(acc[1]-m) + expf(acc[2]-m) + expf(acc[3]-m);
  #pragma unroll
  for (int o = 1; o <= 8; o <<= 1) ssum += __shfl_xor(ssum, o);
  float ls = logf(ssum);
  if (lane < 16){
    float4 o4 = { acc[0]-m-ls, acc[1]-m-ls, acc[2]-m-ls, acc[3]-m-ls };
    *(float4*)(out + (size_t)r * OUTF + c4 * 4) = o4;
  }
}

extern "C" void kernel_launch(void* const* d_in, const int* in_sizes, int n_in,
                              void* d_out, int out_size, void* d_ws, size_t ws_size,
                              hipStream_t stream) {
  const float* X      = (const float*)d_in[0];
  const float* W1     = (const float*)d_in[1];
  const float* W2     = (const float*)d_in[2];
  const int*   a_row  = (const int*)d_in[3];
  const int*   a_col  = (const int*)d_in[4];
  const float* a_val  = (const float*)d_in[5];
  const int*   drop   = (const int*)d_in[6];
  float*       out    = (float*)d_out;

  char* ws = (char*)d_ws;
  int*   row_ptr = (int*)  (ws);                       //   200,704 B
  short* W1p     = (short*)(ws + 200704);              //   262,144 B
  short* W2bT    = (short*)(ws + 462848);              //    32,768 B
  short* XW1b    = (short*)(ws + 495616);              // 25,600,000 B
  short* hb      = (short*)(ws + 26095616);            // 25,600,000 B
  short* HW2b    = (short*)(ws + 51695616);            //  6,400,000 B (end ~58.1 MB)

  k_prep<<<772, 256, 0, stream>>>(a_row, row_ptr, W1, W1p, W2, W2bT);
  k_gemm1<<<(NN + 63)/64, 256, 0, stream>>>(X, W1p, XW1b);
  k_spmm1<<<NN/4, 256, 0, stream>>>(row_ptr, a_col, a_val, XW1b, drop, hb);
  k_gemm2<<<(MTILES + 3)/4, 256, 0, stream>>>(hb, W2bT, HW2b);
  k_spmm2_lsm<<<NN/4, 256, 0, stream>>>(row_ptr, a_col, a_val, HW2b, out);
}